// Round 8
// baseline (217.322 us; speedup 1.0000x reference)
//
#include <hip/hip_runtime.h>

typedef __bf16 bfvec8 __attribute__((ext_vector_type(8)));
typedef float f32x4 __attribute__((ext_vector_type(4)));
typedef unsigned short u16x8 __attribute__((ext_vector_type(8)));
typedef unsigned int u32;

constexpr int C_IN = 128, Wd = 56, Hd = 56, HW = 3136, K_OUT = 256, N_IMG = 32;
constexpr int KKTOT = 1152;      // 128*9
constexpr int WP = 58;           // padded H/W
constexpr size_t XP_ELEMS = (size_t)N_IMG * WP * WP * C_IN;   // 13,776,896
constexpr size_t XP_BYTES = XP_ELEMS * 2;                     // 27,553,792
constexpr size_t WT_ELEMS = (size_t)9 * 4 * 2 * 128 * 32;     // 294,912

// prep-kernel grid partition
constexpr int HALO_BLKS = 456;    // 32 n * 228 halo px * 16 vec8 / 256 thr
constexpr int WT_BLKS   = 1152;   // 294912 / 256
constexpr int XPOSE_BLKS = N_IMG * Hd;   // 1792
constexpr int PREP_GRID = HALO_BLKS + WT_BLKS + XPOSE_BLKS;   // 3400

__device__ inline unsigned short f2bf(float f) {
    union { float f; unsigned u; } v; v.f = f;
    unsigned u = v.u;
    u += 0x7fffu + ((u >> 16) & 1u);   // round-to-nearest-even
    return (unsigned short)(u >> 16);
}

__device__ inline void gld16(const void* g, void* l) {
    __builtin_amdgcn_global_load_lds(
        (const __attribute__((address_space(1))) u32*)g,
        (__attribute__((address_space(3))) u32*)l, 16, 0, 0);
}

// compiler memory fence (no instruction) — pins LDS/global ops vs barriers
#define CFENCE() asm volatile("" ::: "memory")

// ---- Fused pre-pass: halo-zero + weight xform + NCHW->NHWC transpose ------
__global__ __launch_bounds__(256) void prep(const float* __restrict__ x,
                                            const float* __restrict__ wgt,
                                            unsigned short* __restrict__ xp,
                                            unsigned short* __restrict__ wt) {
    __shared__ unsigned short T[Wd * C_IN];   // used by xpose branch only
    const int bx = blockIdx.x;

    if (bx < HALO_BLKS) {
        // zero the halo ring: rows 0,57 full + cols 0,57 (h=1..56): 228 px/n
        int v = bx * 256 + threadIdx.x;       // vec8 index, 3648 per image
        int n = v / 3648, rem = v - n * 3648;
        int p = rem >> 4, c8 = rem & 15;
        int hh, ww;
        if (p < 58)       { hh = 0;       ww = p;       }
        else if (p < 116) { hh = 57;      ww = p - 58;  }
        else if (p < 172) { hh = p - 115; ww = 0;       }
        else              { hh = p - 171; ww = 57;      }
        const u16x8 z = {0, 0, 0, 0, 0, 0, 0, 0};
        *(u16x8*)(xp + ((size_t)(n * WP + hh) * WP + ww) * C_IN + c8 * 8) = z;
        return;
    }
    if (bx < HALO_BLKS + WT_BLKS) {
        // weight OIHW fp32 -> packed bf16; o = (((rs*4+ch)*2+nt)*128+n)*32+kk
        int o = (bx - HALO_BLKS) * 256 + threadIdx.x;
        int kk = o & 31, n = (o >> 5) & 127, nt = (o >> 12) & 1,
            ch = (o >> 13) & 3, rs = o >> 15;
        float v = wgt[(size_t)(nt * 128 + n) * KKTOT + (ch * 32 + kk) * 9 + rs];
        wt[o] = f2bf(v);
        return;
    }
    // x NCHW fp32 -> halo-padded NHWC bf16 (one (n,h) row per block)
    const int nb = bx - (HALO_BLKS + WT_BLKS);
    const int n = nb / Hd, h = nb - n * Hd;
    const float* src = x + (size_t)n * C_IN * HW + h * Wd;
    #pragma unroll
    for (int k = 0; k < 7; ++k) {
        int idx = threadIdx.x + k * 256;      // float4 index 0..1791
        int c = idx / 14, w4 = idx - c * 14;
        const float4 v = *(const float4*)(src + (size_t)c * HW + w4 * 4);
        const int sw = (w4 & 15) * 8;         // (w>>2)&15 == w4 for w4<=13
        T[(w4 * 4 + 0) * C_IN + (c ^ sw)] = f2bf(v.x);
        T[(w4 * 4 + 1) * C_IN + (c ^ sw)] = f2bf(v.y);
        T[(w4 * 4 + 2) * C_IN + (c ^ sw)] = f2bf(v.z);
        T[(w4 * 4 + 3) * C_IN + (c ^ sw)] = f2bf(v.w);
    }
    __syncthreads();
    unsigned short* dst = xp + ((size_t)(n * WP + h + 1) * WP + 1) * C_IN;
    const u16x8* s8 = (const u16x8*)T;
    u16x8* d8 = (u16x8*)dst;
    #pragma unroll
    for (int k = 0; k < 4; ++k) {
        int idx = threadIdx.x + k * 256;
        if (idx < 896) {
            int w = idx >> 4, j8 = idx & 15;
            d8[idx] = s8[w * 16 + (j8 ^ ((w >> 2) & 15))];
        }
    }
}

// ---- Main GEMM: 256x128 block, 4 waves x (128x64 output), ring-2 LDS ------
// LDS-read intensity 11.4 KB/MFLOP (2.7x better than 128^2/4-wave): per step
// a wave reads 12 b128 (8 af + 4 bf) feeding 32 MFMA.  Ring-2 (48 KB) keeps
// LDS from capping residency; depth-1-region prefetch with counted vmcnt(6)
// (region wall time ~600-900cyc covers L2-hit latency; XCD-chunk keeps A in
// the per-XCD L2).  Per step k (fully unrolled):
//   barrier1                      (frag reads of buf (k+1)&1 complete)
//   issue(k+1 -> buf (k+1)&1)     (6 gld16: 4 A-lines + 2 B-lines)
//   s_waitcnt vmcnt(6)            (k's 6 landed; k+1's 6 stay in flight)
//   barrier2                      (k's lines visible to all waves)
//   12 ds_read_b128 + 32 MFMA from buf k&1
// Grid 784 = 8 x 98 XCD-chunked; nt-pairs (shared A-tile) land on same XCD.
__global__ __launch_bounds__(256, 2) void conv_gemm(
    const unsigned short* __restrict__ xp, const unsigned short* __restrict__ wt,
    const float* __restrict__ bias, float* __restrict__ out)
{
    __shared__ __align__(16) unsigned short As[2][256 * 32];  // 2 x 16 KB
    __shared__ __align__(16) unsigned short Bs[2][128 * 32];  // 2 x  8 KB

    const int tid = threadIdx.x;
    const int hbx = blockIdx.x;
    const int lbx = (hbx & 7) * 98 + (hbx >> 3);   // XCD-chunked, bijective
    const int nt  = lbx & 1;
    const int mtile = (lbx >> 1) * 256;

    // swizzled chunk this lane must FETCH so that slot (r, tid&3) holds it
    const int cg8 = ((tid & 3) ^ ((tid >> 3) & 3)) * 8;   // halfword offset

    const unsigned short* gA[4];
    #pragma unroll
    for (int L = 0; L < 4; ++L) {
        int m = mtile + L * 64 + (tid >> 2);
        int ni = m / HW; int hw = m - ni * HW; int h = hw / Wd; int w = hw - h * Wd;
        gA[L] = xp + ((size_t)(ni * WP + h + 1) * WP + (w + 1)) * C_IN + cg8;
    }
    // wt base for this block's n-tile + this lane's row/swizzle-chunk
    const unsigned short* gB = wt + (size_t)nt * 4096 + (size_t)(tid & 0xFC) * 8 + cg8;

    const int wave = tid >> 6, lane = tid & 63;
    const int wrow = (wave >> 1) * 128, wcol = (wave & 1) * 64;
    const int r16 = lane & 15, quad = lane >> 4;
    const int qsw = (quad ^ ((r16 >> 1) & 3)) * 8;   // swizzled read offset

    const f32x4 zero4 = {0.f, 0.f, 0.f, 0.f};
    f32x4 acc[8][4];
    #pragma unroll
    for (int i = 0; i < 8; ++i)
        #pragma unroll
        for (int j = 0; j < 4; ++j)
            acc[i][j] = zero4;

    // issue the 6 staging loads for `step` into ring buffer `buf`
    auto issue = [&](int step, int buf) {
        const int rs = step >> 2, ch = step & 3;
        const int dr = rs / 3 - 1, dc = rs % 3 - 1;
        const int aoff = (dr * WP + dc) * C_IN + ch * 32;   // wave-uniform
        const size_t boff = (size_t)step * 8192;
        #pragma unroll
        for (int L = 0; L < 4; ++L)
            gld16(gA[L] + aoff, (void*)(As[buf] + L * 2048 + tid * 8));
        gld16(gB + boff,        (void*)(Bs[buf] + tid * 8));
        gld16(gB + boff + 2048, (void*)(Bs[buf] + 2048 + tid * 8));
    };

    issue(0, 0);                                  // prologue prefetch

    #pragma unroll
    for (int step = 0; step < 36; ++step) {
        const int cur = step & 1;

        CFENCE(); __builtin_amdgcn_s_barrier(); CFENCE();   // WAR on buf cur^1
        if (step < 35) {
            issue(step + 1, cur ^ 1);
            asm volatile("s_waitcnt vmcnt(6)" ::: "memory");
        } else {
            asm volatile("s_waitcnt vmcnt(0)" ::: "memory");
        }
        CFENCE(); __builtin_amdgcn_s_barrier(); CFENCE();   // step's loads visible

        bfvec8 bf[4];
        #pragma unroll
        for (int ni = 0; ni < 4; ++ni)
            bf[ni] = *(const bfvec8*)&Bs[cur][(wcol + ni * 16 + r16) * 32 + qsw];

        #pragma unroll
        for (int mi = 0; mi < 8; ++mi) {
            const bfvec8 af = *(const bfvec8*)&As[cur][(wrow + mi * 16 + r16) * 32 + qsw];
            #pragma unroll
            for (int ni = 0; ni < 4; ++ni)
                acc[mi][ni] = __builtin_amdgcn_mfma_f32_16x16x32_bf16(
                    af, bf[ni], acc[mi][ni], 0, 0, 0);
        }
    }

    // epilogue: D col=lane&15 -> k, row=quad*4+i -> m; i is m-consecutive ->
    // hwe-consecutive (3136%4==0, base%4==0) -> dwordx4 stores
    const int ntile = nt * 128;
    #pragma unroll
    for (int ni = 0; ni < 4; ++ni) {
        const int k = ntile + wcol + ni * 16 + r16;
        const float bb = bias[k];
        #pragma unroll
        for (int mi = 0; mi < 8; ++mi) {
            const int mb  = mtile + wrow + mi * 16 + quad * 4;
            const int ne  = mb / HW;
            const int hwe = mb - ne * HW;
            f32x4 v;
            #pragma unroll
            for (int i = 0; i < 4; ++i) v[i] = acc[mi][ni][i] + bb;
            *(f32x4*)(out + ((size_t)ne * K_OUT + k) * HW + hwe) = v;
        }
    }
}

extern "C" void kernel_launch(void* const* d_in, const int* in_sizes, int n_in,
                              void* d_out, int out_size, void* d_ws, size_t ws_size,
                              hipStream_t stream) {
    const float* x    = (const float*)d_in[0];
    const float* wgt  = (const float*)d_in[1];
    const float* bias = (const float*)d_in[2];
    float* out = (float*)d_out;

    unsigned short* xp = (unsigned short*)d_ws;
    unsigned short* wt = (unsigned short*)((char*)d_ws + XP_BYTES);

    prep<<<dim3(PREP_GRID), dim3(256), 0, stream>>>(x, wgt, xp, wt);
    conv_gemm<<<dim3(784), dim3(256), 0, stream>>>(xp, wt, bias, out);
}

// Round 9
// 207.002 us; speedup vs baseline: 1.0499x; 1.0499x over previous
//
#include <hip/hip_runtime.h>

typedef __bf16 bfvec8 __attribute__((ext_vector_type(8)));
typedef float f32x4 __attribute__((ext_vector_type(4)));
typedef unsigned short u16x8 __attribute__((ext_vector_type(8)));
typedef unsigned int u32;

constexpr int C_IN = 128, Wd = 56, Hd = 56, HW = 3136, K_OUT = 256, N_IMG = 32;
constexpr int KKTOT = 1152;      // 128*9
constexpr int WP = 58;           // padded H/W
constexpr size_t XP_ELEMS = (size_t)N_IMG * WP * WP * C_IN;   // 13,776,896
constexpr size_t XP_BYTES = XP_ELEMS * 2;                     // 27,553,792
constexpr size_t WT_ELEMS = (size_t)9 * 4 * 2 * 128 * 32;     // 294,912

// prep-kernel grid partition
constexpr int HALO_BLKS = 456;    // 32 n * 228 halo px * 16 vec8 / 256 thr
constexpr int WT_BLKS   = 1152;   // 294912 / 256
constexpr int XPOSE_BLKS = N_IMG * Hd;   // 1792
constexpr int PREP_GRID = HALO_BLKS + WT_BLKS + XPOSE_BLKS;   // 3400

__device__ inline unsigned short f2bf(float f) {
    union { float f; unsigned u; } v; v.f = f;
    unsigned u = v.u;
    u += 0x7fffu + ((u >> 16) & 1u);   // round-to-nearest-even
    return (unsigned short)(u >> 16);
}

__device__ inline void gld16(const void* g, void* l) {
    __builtin_amdgcn_global_load_lds(
        (const __attribute__((address_space(1))) u32*)g,
        (__attribute__((address_space(3))) u32*)l, 16, 0, 0);
}

// compiler memory fence (no instruction) — pins LDS/global ops vs barriers
#define CFENCE() asm volatile("" ::: "memory")

// ---- Fused pre-pass: halo-zero + weight xform + NCHW->NHWC transpose ------
__global__ __launch_bounds__(256) void prep(const float* __restrict__ x,
                                            const float* __restrict__ wgt,
                                            unsigned short* __restrict__ xp,
                                            unsigned short* __restrict__ wt) {
    __shared__ unsigned short T[Wd * C_IN];   // used by xpose branch only
    const int bx = blockIdx.x;

    if (bx < HALO_BLKS) {
        // zero the halo ring: rows 0,57 full + cols 0,57 (h=1..56): 228 px/n
        int v = bx * 256 + threadIdx.x;       // vec8 index, 3648 per image
        int n = v / 3648, rem = v - n * 3648;
        int p = rem >> 4, c8 = rem & 15;
        int hh, ww;
        if (p < 58)       { hh = 0;       ww = p;       }
        else if (p < 116) { hh = 57;      ww = p - 58;  }
        else if (p < 172) { hh = p - 115; ww = 0;       }
        else              { hh = p - 171; ww = 57;      }
        const u16x8 z = {0, 0, 0, 0, 0, 0, 0, 0};
        *(u16x8*)(xp + ((size_t)(n * WP + hh) * WP + ww) * C_IN + c8 * 8) = z;
        return;
    }
    if (bx < HALO_BLKS + WT_BLKS) {
        // weight OIHW fp32 -> packed bf16; o = (((rs*4+ch)*2+nt)*128+n)*32+kk
        int o = (bx - HALO_BLKS) * 256 + threadIdx.x;
        int kk = o & 31, n = (o >> 5) & 127, nt = (o >> 12) & 1,
            ch = (o >> 13) & 3, rs = o >> 15;
        float v = wgt[(size_t)(nt * 128 + n) * KKTOT + (ch * 32 + kk) * 9 + rs];
        wt[o] = f2bf(v);
        return;
    }
    // x NCHW fp32 -> halo-padded NHWC bf16 (one (n,h) row per block)
    const int nb = bx - (HALO_BLKS + WT_BLKS);
    const int n = nb / Hd, h = nb - n * Hd;
    const float* src = x + (size_t)n * C_IN * HW + h * Wd;
    #pragma unroll
    for (int k = 0; k < 7; ++k) {
        int idx = threadIdx.x + k * 256;      // float4 index 0..1791
        int c = idx / 14, w4 = idx - c * 14;
        const float4 v = *(const float4*)(src + (size_t)c * HW + w4 * 4);
        const int sw = (w4 & 15) * 8;         // (w>>2)&15 == w4 for w4<=13
        T[(w4 * 4 + 0) * C_IN + (c ^ sw)] = f2bf(v.x);
        T[(w4 * 4 + 1) * C_IN + (c ^ sw)] = f2bf(v.y);
        T[(w4 * 4 + 2) * C_IN + (c ^ sw)] = f2bf(v.z);
        T[(w4 * 4 + 3) * C_IN + (c ^ sw)] = f2bf(v.w);
    }
    __syncthreads();
    unsigned short* dst = xp + ((size_t)(n * WP + h + 1) * WP + 1) * C_IN;
    const u16x8* s8 = (const u16x8*)T;
    u16x8* d8 = (u16x8*)dst;
    #pragma unroll
    for (int k = 0; k < 4; ++k) {
        int idx = threadIdx.x + k * 256;
        if (idx < 896) {
            int w = idx >> 4, j8 = idx & 15;
            d8[idx] = s8[w * 16 + (j8 ^ ((w >> 2) & 15))];
        }
    }
}

// ---- Main GEMM: R3 geometry at 4-resident ---------------------------------
// 128x128 block, 4 waves x (64x64), ring-2 LDS (32 KB), depth-1 prefetch
// with counted vmcnt(4), XCD-chunked swizzle, fully unrolled.
// __launch_bounds__(256,4): cap regs/wave at 128 (64 acc AGPR + <=64 VGPR;
// R2 compiled the same schedule at VGPR=64).  4 co-resident blocks give the
// cross-block anti-phase overlap this family lives on: one block's LDS-read
// burst fills another's MFMA/latency pockets.  af streamed one-at-a-time
// (live frags = bf[4]+af = 20 VGPR) to help the allocator.
// Per step k: barrier (WAR buf k^1) -> issue(k+1 -> buf k^1) -> vmcnt(4)
// (k's 4 landed, k+1's in flight) -> barrier -> 8 ds_read + 16 MFMA.
__global__ __launch_bounds__(256, 4) void conv_gemm(
    const unsigned short* __restrict__ xp, const unsigned short* __restrict__ wt,
    const float* __restrict__ bias, float* __restrict__ out)
{
    __shared__ __align__(16) unsigned short As[2][128 * 32];  // 2 x 8 KB
    __shared__ __align__(16) unsigned short Bs[2][128 * 32];  // 2 x 8 KB

    const int tid = threadIdx.x;
    const int hbx = blockIdx.x;
    const int lbx = (hbx & 7) * 196 + (hbx >> 3);   // XCD-chunked, bijective
    const int nt  = lbx & 1;
    const int mtile = (lbx >> 1) * 128;

    // swizzled chunk this lane must FETCH so that slot (r, tid&3) holds it
    const int cg8 = ((tid & 3) ^ ((tid >> 3) & 3)) * 8;   // halfword offset

    const unsigned short *gA0, *gA1;
    {
        int mrow = tid >> 2;
        int m = mtile + mrow;
        int ni = m / HW; int hw = m - ni * HW; int h = hw / Wd; int w = hw - h * Wd;
        gA0 = xp + ((size_t)(ni * WP + h + 1) * WP + (w + 1)) * C_IN + cg8;
        m += 64;
        ni = m / HW; hw = m - ni * HW; h = hw / Wd; w = hw - h * Wd;
        gA1 = xp + ((size_t)(ni * WP + h + 1) * WP + (w + 1)) * C_IN + cg8;
    }
    // wt base for this block's n-tile + this lane's row/swizzle-chunk
    const unsigned short* gB = wt + (size_t)nt * 4096 + (size_t)(tid & 0xFC) * 8 + cg8;

    const int wave = tid >> 6, lane = tid & 63;
    const int wrow = (wave >> 1) * 64, wcol = (wave & 1) * 64;
    const int r16 = lane & 15, quad = lane >> 4;
    const int qsw = (quad ^ ((r16 >> 1) & 3)) * 8;   // swizzled read offset

    const f32x4 zero4 = {0.f, 0.f, 0.f, 0.f};
    f32x4 acc[4][4];
    #pragma unroll
    for (int i = 0; i < 4; ++i)
        #pragma unroll
        for (int j = 0; j < 4; ++j)
            acc[i][j] = zero4;

    // issue the 4 staging loads for `step` into buffer `buf`
    auto issue = [&](int step, int buf) {
        const int rs = step >> 2, ch = step & 3;
        const int dr = rs / 3 - 1, dc = rs % 3 - 1;
        const int aoff = (dr * WP + dc) * C_IN + ch * 32;   // wave-uniform
        const size_t boff = (size_t)step * 8192;
        gld16(gA0 + aoff, (void*)(As[buf] + tid * 8));
        gld16(gA1 + aoff, (void*)(As[buf] + 2048 + tid * 8));
        gld16(gB + boff,        (void*)(Bs[buf] + tid * 8));
        gld16(gB + boff + 2048, (void*)(Bs[buf] + 2048 + tid * 8));
    };

    issue(0, 0);                                  // prologue prefetch

    #pragma unroll
    for (int step = 0; step < 36; ++step) {
        const int cur = step & 1;

        CFENCE(); __builtin_amdgcn_s_barrier(); CFENCE();   // WAR on buf cur^1
        if (step < 35) {
            issue(step + 1, cur ^ 1);
            asm volatile("s_waitcnt vmcnt(4)" ::: "memory");  // step's 4 landed
        } else {
            asm volatile("s_waitcnt vmcnt(0)" ::: "memory");
        }
        CFENCE(); __builtin_amdgcn_s_barrier(); CFENCE();   // visible to all waves

        bfvec8 bf[4];
        #pragma unroll
        for (int ni = 0; ni < 4; ++ni)
            bf[ni] = *(const bfvec8*)&Bs[cur][(wcol + ni * 16 + r16) * 32 + qsw];

        #pragma unroll
        for (int mi = 0; mi < 4; ++mi) {
            const bfvec8 af = *(const bfvec8*)&As[cur][(wrow + mi * 16 + r16) * 32 + qsw];
            #pragma unroll
            for (int ni = 0; ni < 4; ++ni)
                acc[mi][ni] = __builtin_amdgcn_mfma_f32_16x16x32_bf16(
                    af, bf[ni], acc[mi][ni], 0, 0, 0);
        }
    }

    // epilogue: D col=lane&15 -> k, row=quad*4+i -> m; i is m-consecutive ->
    // hwe-consecutive (3136%4==0, base%4==0) -> dwordx4 stores
    const int ntile = nt * 128;
    #pragma unroll
    for (int ni = 0; ni < 4; ++ni) {
        const int k = ntile + wcol + ni * 16 + r16;
        const float bb = bias[k];
        #pragma unroll
        for (int mi = 0; mi < 4; ++mi) {
            const int mb  = mtile + wrow + mi * 16 + quad * 4;
            const int ne  = mb / HW;
            const int hwe = mb - ne * HW;
            f32x4 v;
            #pragma unroll
            for (int i = 0; i < 4; ++i) v[i] = acc[mi][ni][i] + bb;
            *(f32x4*)(out + ((size_t)ne * K_OUT + k) * HW + hwe) = v;
        }
    }
}

extern "C" void kernel_launch(void* const* d_in, const int* in_sizes, int n_in,
                              void* d_out, int out_size, void* d_ws, size_t ws_size,
                              hipStream_t stream) {
    const float* x    = (const float*)d_in[0];
    const float* wgt  = (const float*)d_in[1];
    const float* bias = (const float*)d_in[2];
    float* out = (float*)d_out;

    unsigned short* xp = (unsigned short*)d_ws;
    unsigned short* wt = (unsigned short*)((char*)d_ws + XP_BYTES);

    prep<<<dim3(PREP_GRID), dim3(256), 0, stream>>>(x, wgt, xp, wt);
    conv_gemm<<<dim3(1568), dim3(256), 0, stream>>>(xp, wt, bias, out);
}